// Round 12
// baseline (84.391 us; speedup 1.0000x reference)
//
#include <hip/hip_runtime.h>
#include <hip/hip_bf16.h>
#include <math.h>

#define NB 2
#define NS 2048
#define NHID 768
#define NH 12
#define NDH 64
#define NWIN 128

typedef __attribute__((ext_vector_type(8))) short bf16x8;
typedef __attribute__((ext_vector_type(4))) float f32x4;

__device__ inline unsigned short f2b(float f) {
    union { float f; unsigned int i; } x; x.f = f;
    unsigned int r = x.i + 0x7FFFu + ((x.i >> 16) & 1u);   // RNE
    return (unsigned short)(r >> 16);
}
// XCD-chunked bijective remap (nwg % 8 == 0): XCD k gets contiguous chunk
__device__ inline int xcd_remap(int flat, int nwg) {
    return (flat & 7) * (nwg >> 3) + (flat >> 3);
}
// async global->LDS, 16B per lane (LDS dest = wave-uniform base + lane*16)
__device__ __forceinline__ void gload_lds16(const void* g, void* l) {
    __builtin_amdgcn_global_load_lds((const __attribute__((address_space(1))) void*)g,
                                     (__attribute__((address_space(3))) void*)l, 16, 0, 0);
}

union Frag { bf16x8 v; unsigned long long q[2]; uint4 u; };

// ---------------- fused prep: convT (blocks 0..575) + rope (blocks 576..6719) --------
__global__ __launch_bounds__(256) void k_prep(const float* __restrict__ x,
                                              __hip_bfloat16* __restrict__ rb,
                                              __hip_bfloat16* __restrict__ xb,
                                              const float* __restrict__ w0, const float* __restrict__ w1,
                                              const float* __restrict__ w2, const float* __restrict__ w3,
                                              __hip_bfloat16* o0, __hip_bfloat16* o1,
                                              __hip_bfloat16* o2, __hip_bfloat16* o3) {
    int bid = blockIdx.x;
    int t = threadIdx.x;
    if (bid < 576) {
        int wsel = bid / 144, r = bid % 144;
        int kx = r % 12, ny = r / 12;
        const float* W; __hip_bfloat16* O;
        switch (wsel) {
            case 0: W = w0; O = o0; break;
            case 1: W = w1; O = o1; break;
            case 2: W = w2; O = o2; break;
            default: W = w3; O = o3; break;
        }
        __shared__ float tile[64][65];
        int k0 = kx * 64, n0 = ny * 64;
        int rr = t >> 4, cc = (t & 15) * 4;
#pragma unroll
        for (int u = 0; u < 4; ++u) {
            int row = rr + u * 16;
            float4 f = *(const float4*)(W + (size_t)(k0 + row) * NHID + n0 + cc);
            tile[row][cc] = f.x; tile[row][cc + 1] = f.y;
            tile[row][cc + 2] = f.z; tile[row][cc + 3] = f.w;
        }
        __syncthreads();
#pragma unroll
        for (int u = 0; u < 4; ++u) {
            int n = rr + u * 16;
            ushort4 s = { f2b(tile[cc + 0][n]), f2b(tile[cc + 1][n]),
                          f2b(tile[cc + 2][n]), f2b(tile[cc + 3][n]) };
            *(ushort4*)((unsigned short*)O + (size_t)(n0 + n) * NHID + k0 + cc) = s;
        }
    } else {
        int idx = (bid - 576) * 256 + t;
        int f = idx & 31;
        int h = (idx >> 5) % NH;
        int bs = idx / (32 * NH);
        int s = bs & (NS - 1);
        int base = bs * NHID + h * NDH;
        float x1 = x[base + f], x2 = x[base + 32 + f];
        float inv = exp2f(-0.4152410118609203f * (float)f);   // 10000^(-f/32)
        float ang = (float)s * inv;
        float c = cosf(ang), sn = sinf(ang);
        ((unsigned short*)rb)[base + f]      = f2b(x1 * c - x2 * sn);
        ((unsigned short*)rb)[base + 32 + f] = f2b(x2 * c + x1 * sn);
        ((unsigned short*)xb)[base + f]      = f2b(x1);
        ((unsigned short*)xb)[base + 32 + f] = f2b(x2);
    }
}

// ---------------- 1-wave barrier-free MFMA GEMM -------------------------------------
// 64 threads = 1 wave per block; tile 64x64, BK=32, dbuf LDS (16 KB), gload_lds
// staging, per-wave counted vmcnt, ZERO barriers. Per tile t:
//   STAGE(buf^1, t+1) [8 DMA]; s_waitcnt vmcnt(8) [= tile-t loads done]; COMPUTE(buf).
// Same-wave in-order issue makes buffer reuse safe (ds_reads of buf issue before the
// next DMA that overwrites it; DMA write arrives >=200cy later).
// Swizzle (rule #21): phys chunk p of row r holds global k-chunk p^((r>>1)&3); staged
// via pre-permuted source chunk (t&3)^((t>>3)&3); read at g^((r16>>1)&3) -> lane-
// uniform logical chunk g, identical permutation for A and B (contraction-invariant).
__device__ __forceinline__ void gemm1w(const __hip_bfloat16* __restrict__ A,
                                       const __hip_bfloat16* __restrict__ Wt,
                                       const float* __restrict__ bias,
                                       __hip_bfloat16* __restrict__ Cb,
                                       float* __restrict__ Cf, float scale,
                                       int m0, int n0) {
    __shared__ __attribute__((aligned(16))) unsigned short As[2][64][32];
    __shared__ __attribute__((aligned(16))) unsigned short Bs[2][64][32];
    const int t = threadIdx.x;            // 0..63
    const int g = t >> 4, r16 = t & 15;
    const int rho = (r16 >> 1) & 3;       // read-side XOR

    f32x4 acc[4][4];
#pragma unroll
    for (int i = 0; i < 4; ++i)
#pragma unroll
        for (int j = 0; j < 4; ++j) acc[i][j] = (f32x4){0.f, 0.f, 0.f, 0.f};

    const int srow = t >> 2;                        // 0..15 (row within 16-row group)
    const int gslot = (t & 3) ^ ((t >> 3) & 3);     // inverse-swizzled source chunk
    const unsigned short* gA = (const unsigned short*)A + (size_t)(m0 + srow) * NHID + gslot * 8;
    const unsigned short* gB = (const unsigned short*)Wt + (size_t)(n0 + srow) * NHID + gslot * 8;

#define STAGE1(b, tt) do {                                                      \
    _Pragma("unroll")                                                           \
    for (int c = 0; c < 4; ++c)                                                 \
        gload_lds16(gA + (size_t)c * 16 * NHID + (tt) * 32, (char*)&As[b][0][0] + c * 1024); \
    _Pragma("unroll")                                                           \
    for (int c = 0; c < 4; ++c)                                                 \
        gload_lds16(gB + (size_t)c * 16 * NHID + (tt) * 32, (char*)&Bs[b][0][0] + c * 1024); \
} while (0)

#define COMPUTE1(b) do {                                                        \
    Frag af[4], bf[4];                                                          \
    _Pragma("unroll")                                                           \
    for (int mi = 0; mi < 4; ++mi)                                              \
        af[mi].u = *(const uint4*)&As[b][mi * 16 + r16][(g ^ rho) * 8];         \
    _Pragma("unroll")                                                           \
    for (int ni = 0; ni < 4; ++ni)                                              \
        bf[ni].u = *(const uint4*)&Bs[b][ni * 16 + r16][(g ^ rho) * 8];         \
    _Pragma("unroll")                                                           \
    for (int mi = 0; mi < 4; ++mi)                                              \
        _Pragma("unroll")                                                       \
        for (int ni = 0; ni < 4; ++ni)                                          \
            acc[mi][ni] = __builtin_amdgcn_mfma_f32_16x16x32_bf16(af[mi].v, bf[ni].v, acc[mi][ni], 0, 0, 0); \
} while (0)

    STAGE1(0, 0);
#pragma unroll
    for (int it = 0; it < 12; ++it) {
        STAGE1(1, 2 * it + 1);
        asm volatile("s_waitcnt vmcnt(8)" ::: "memory");   // tile 2it resident
        COMPUTE1(0);
        if (it < 11) {
            STAGE1(0, 2 * it + 2);
            asm volatile("s_waitcnt vmcnt(8)" ::: "memory");
        } else {
            asm volatile("s_waitcnt vmcnt(0)" ::: "memory");
        }
        COMPUTE1(1);                                       // tile 2it+1
    }
#undef STAGE1
#undef COMPUTE1

#pragma unroll
    for (int mi = 0; mi < 4; ++mi)
#pragma unroll
        for (int ni = 0; ni < 4; ++ni)
#pragma unroll
            for (int r = 0; r < 4; ++r) {
                int m = m0 + mi * 16 + 4 * g + r;
                int n = n0 + ni * 16 + r16;
                float v = (acc[mi][ni][r] + bias[n]) * scale;
                if (Cb) ((unsigned short*)Cb)[(size_t)m * NHID + n] = f2b(v);
                else    Cf[(size_t)m * NHID + n] = v;
            }
}

// fused QKV projection: 2304 one-wave blocks, XCD-chunked, n-fastest for A L2 reuse.
__global__ __launch_bounds__(64) void k_gemm_qkv(const __hip_bfloat16* __restrict__ rb,
                                                 const __hip_bfloat16* __restrict__ xb,
                                                 const __hip_bfloat16* __restrict__ WtQ,
                                                 const __hip_bfloat16* __restrict__ WtK,
                                                 const __hip_bfloat16* __restrict__ WtV,
                                                 const float* __restrict__ bq,
                                                 const float* __restrict__ bk,
                                                 const float* __restrict__ bv,
                                                 __hip_bfloat16* qb, __hip_bfloat16* kb,
                                                 __hip_bfloat16* vb) {
    int id = xcd_remap(blockIdx.x, 2304);
    int z = id / 768, rem = id % 768;
    int ty = rem / 12, tx = rem % 12;      // n fastest: 12 consecutive ids share A-panel
    const __hip_bfloat16 *A, *W; const float* bias; __hip_bfloat16* C; float scale;
    switch (z) {
        case 0:  A = rb; W = WtQ; bias = bq; C = qb; scale = 0.125f; break;
        case 1:  A = rb; W = WtK; bias = bk; C = kb; scale = 1.0f;   break;
        default: A = xb; W = WtV; bias = bv; C = vb; scale = 1.0f;   break;
    }
    gemm1w(A, W, bias, C, nullptr, scale, ty * 64, tx * 64);
}

// output projection: 768 one-wave blocks.
__global__ __launch_bounds__(64) void k_gemm_out(const __hip_bfloat16* __restrict__ A,
                                                 const __hip_bfloat16* __restrict__ Wt,
                                                 const float* __restrict__ bias,
                                                 float* __restrict__ Cf) {
    int id = xcd_remap(blockIdx.x, 768);
    int ty = id / 12, tx = id % 12;
    gemm1w(A, Wt, bias, nullptr, Cf, 1.0f, ty * 64, tx * 64);
}

// ---------------- sliding-window flash attention, MFMA + T14 async-STAGE (R11) -------
__global__ __launch_bounds__(256) void k_attn(const __hip_bfloat16* __restrict__ q,
                                              const __hip_bfloat16* __restrict__ kmat,
                                              const __hip_bfloat16* __restrict__ vmat,
                                              const int* __restrict__ am,
                                              __hip_bfloat16* __restrict__ o) {
    __shared__ unsigned short Ks[64][72];   // [key][d]
    __shared__ unsigned short Vt[64][72];   // [d][key]
    __shared__ float kmask[64];
    const int t = threadIdx.x;
    const int h = blockIdx.y, b = blockIdx.z;
    const int i0 = blockIdx.x * 64;
    const int w = t >> 6, lane = t & 63;
    const int g = lane >> 4, r16 = lane & 15;
    const int qrow = i0 + w * 16 + r16;

    Frag qf[2];
    {
        const unsigned short* qp = (const unsigned short*)q + ((size_t)(b * NS) + qrow) * NHID + h * NDH;
        qf[0].q[0] = *(const unsigned long long*)(qp + 4 * g);
        qf[0].q[1] = *(const unsigned long long*)(qp + 16 + 4 * g);
        qf[1].q[0] = *(const unsigned long long*)(qp + 32 + 4 * g);
        qf[1].q[1] = *(const unsigned long long*)(qp + 48 + 4 * g);
    }
    float m_run = -1e30f, l_run = 0.f;
    f32x4 oacc[4];
#pragma unroll
    for (int i = 0; i < 4; ++i) oacc[i] = (f32x4){0.f, 0.f, 0.f, 0.f};

    const int ktL = (i0 == 0) ? 2 : (i0 == 64) ? 1 : 0;
    const int ktH = (i0 == NS - 64) ? 2 : (i0 == NS - 128) ? 3 : 4;

    uint4 pK0, pK1, pV0, pV1; float pm = 0.f;

#define LOADREGS(KT) do {                                                        \
    int j0_ = i0 - 128 + (KT) * 64;                                              \
    const unsigned short* kp_ = (const unsigned short*)kmat +                    \
        ((size_t)(b * NS) + j0_ + (t >> 2)) * NHID + h * NDH + (t & 3) * 16;     \
    pK0 = *(const uint4*)kp_;                                                    \
    pK1 = *(const uint4*)(kp_ + 8);                                              \
    const unsigned short* vp_ = (const unsigned short*)vmat +                    \
        ((size_t)(b * NS) + j0_ + 2 * (t & 31)) * NHID + h * NDH + (t >> 5) * 8; \
    pV0 = *(const uint4*)vp_;                                                    \
    pV1 = *(const uint4*)(vp_ + NHID);                                           \
    if (t < 64) pm = (am[b * NS + j0_ + t] != 0) ? 0.f : -1e30f;                 \
} while (0)

    LOADREGS(ktL);
    for (int kt = ktL; kt <= ktH; ++kt) {
        const int j0 = i0 - 128 + kt * 64;
        {
            *(uint4*)&Ks[t >> 2][(t & 3) * 16]     = pK0;
            *(uint4*)&Ks[t >> 2][(t & 3) * 16 + 8] = pK1;
            union { uint4 u; unsigned short s[8]; } a0, a1;
            a0.u = pV0; a1.u = pV1;
#pragma unroll
            for (int e = 0; e < 8; ++e) {
                unsigned int pk = (unsigned int)a0.s[e] | ((unsigned int)a1.s[e] << 16);
                *(unsigned int*)&Vt[(t >> 5) * 8 + e][2 * (t & 31)] = pk;
            }
            if (t < 64) kmask[t] = pm;
        }
        if (kt < ktH) LOADREGS(kt + 1);        // prefetch flies during compute
        asm volatile("s_waitcnt lgkmcnt(0)" ::: "memory");
        __builtin_amdgcn_s_barrier();          // raw: prefetch NOT drained

        f32x4 sacc[4];
#pragma unroll
        for (int i = 0; i < 4; ++i) sacc[i] = (f32x4){0.f, 0.f, 0.f, 0.f};
#pragma unroll
        for (int mi = 0; mi < 4; ++mi) {
            Frag kf0, kf1;
            const unsigned short* pk = &Ks[mi * 16 + r16][0];
            kf0.q[0] = *(const unsigned long long*)(pk + 4 * g);
            kf0.q[1] = *(const unsigned long long*)(pk + 16 + 4 * g);
            kf1.q[0] = *(const unsigned long long*)(pk + 32 + 4 * g);
            kf1.q[1] = *(const unsigned long long*)(pk + 48 + 4 * g);
            sacc[mi] = __builtin_amdgcn_mfma_f32_16x16x32_bf16(kf0.v, qf[0].v, sacc[mi], 0, 0, 0);
            sacc[mi] = __builtin_amdgcn_mfma_f32_16x16x32_bf16(kf1.v, qf[1].v, sacc[mi], 0, 0, 0);
        }

        float p[4][4];
        float tmax = -1e30f;
#pragma unroll
        for (int mi = 0; mi < 4; ++mi)
#pragma unroll
            for (int r = 0; r < 4; ++r) {
                int key = j0 + mi * 16 + 4 * g + r;
                float s = sacc[mi][r] + kmask[mi * 16 + 4 * g + r];
                int d = qrow - key; d = d < 0 ? -d : d;
                if (d >= NWIN) s = -1e30f;
                p[mi][r] = s;
                tmax = fmaxf(tmax, s);
            }
        tmax = fmaxf(tmax, __shfl_xor(tmax, 16));
        tmax = fmaxf(tmax, __shfl_xor(tmax, 32));
        float mnew = fmaxf(m_run, tmax);
        float psum = 0.f;
#pragma unroll
        for (int mi = 0; mi < 4; ++mi)
#pragma unroll
            for (int r = 0; r < 4; ++r) {
                float pv = __expf(p[mi][r] - mnew);
                p[mi][r] = pv;
                psum += pv;
            }
        psum += __shfl_xor(psum, 16);
        psum += __shfl_xor(psum, 32);
        float alpha = __expf(m_run - mnew);
        m_run = mnew;
        l_run = l_run * alpha + psum;
#pragma unroll
        for (int mi = 0; mi < 4; ++mi)
#pragma unroll
            for (int r = 0; r < 4; ++r) oacc[mi][r] *= alpha;

        Frag pf[2];
#pragma unroll
        for (int ks2 = 0; ks2 < 2; ++ks2) {
            union { bf16x8 v; unsigned short s[8]; } pp;
#pragma unroll
            for (int r = 0; r < 4; ++r) {
                pp.s[r]     = f2b(p[2 * ks2][r]);
                pp.s[r + 4] = f2b(p[2 * ks2 + 1][r]);
            }
            pf[ks2].v = pp.v;
        }

#pragma unroll
        for (int mi = 0; mi < 4; ++mi) {
            Frag vf0, vf1;
            const unsigned short* pv = &Vt[mi * 16 + r16][0];
            vf0.q[0] = *(const unsigned long long*)(pv + 4 * g);
            vf0.q[1] = *(const unsigned long long*)(pv + 16 + 4 * g);
            vf1.q[0] = *(const unsigned long long*)(pv + 32 + 4 * g);
            vf1.q[1] = *(const unsigned long long*)(pv + 48 + 4 * g);
            oacc[mi] = __builtin_amdgcn_mfma_f32_16x16x32_bf16(vf0.v, pf[0].v, oacc[mi], 0, 0, 0);
            oacc[mi] = __builtin_amdgcn_mfma_f32_16x16x32_bf16(vf1.v, pf[1].v, oacc[mi], 0, 0, 0);
        }
        asm volatile("s_waitcnt lgkmcnt(0)" ::: "memory");
        __builtin_amdgcn_s_barrier();
    }
#undef LOADREGS

    float inv_l = 1.0f / l_run;
    unsigned short* op = (unsigned short*)o + ((size_t)(b * NS) + qrow) * NHID + h * NDH;
#pragma unroll
    for (int mi = 0; mi < 4; ++mi) {
        ushort4 s = { f2b(oacc[mi][0] * inv_l), f2b(oacc[mi][1] * inv_l),
                      f2b(oacc[mi][2] * inv_l), f2b(oacc[mi][3] * inv_l) };
        *(ushort4*)(op + mi * 16 + 4 * g) = s;
    }
}

extern "C" void kernel_launch(void* const* d_in, const int* in_sizes, int n_in,
                              void* d_out, int out_size, void* d_ws, size_t ws_size,
                              hipStream_t stream) {
    (void)in_sizes; (void)n_in; (void)out_size; (void)ws_size;
    const float* x  = (const float*)d_in[0];
    const int*   am = (const int*)d_in[1];
    const float* Wq = (const float*)d_in[2];
    const float* bq = (const float*)d_in[3];
    const float* Wk = (const float*)d_in[4];
    const float* bk = (const float*)d_in[5];
    const float* Wv = (const float*)d_in[6];
    const float* bv = (const float*)d_in[7];
    const float* Wo = (const float*)d_in[8];
    const float* bo = (const float*)d_in[9];
    float* out = (float*)d_out;
    float* ws  = (float*)d_ws;

    __hip_bfloat16* rb  = (__hip_bfloat16*)(ws);             // 4096x768 bf16
    __hip_bfloat16* xb  = (__hip_bfloat16*)(ws + 1572864);
    __hip_bfloat16* WtQ = (__hip_bfloat16*)(ws + 3145728);   // 768x768 bf16 each
    __hip_bfloat16* WtK = (__hip_bfloat16*)(ws + 3440640);
    __hip_bfloat16* WtV = (__hip_bfloat16*)(ws + 3735552);
    __hip_bfloat16* WtO = (__hip_bfloat16*)(ws + 4030464);
    __hip_bfloat16* qb  = (__hip_bfloat16*)(ws + 4325376);   // 4096x768 bf16 each
    __hip_bfloat16* kb  = (__hip_bfloat16*)(ws + 5898240);
    __hip_bfloat16* vb  = (__hip_bfloat16*)(ws + 7471104);
    __hip_bfloat16* aob = (__hip_bfloat16*)(ws + 9043968);

    k_prep<<<576 + 6144, 256, 0, stream>>>(x, rb, xb, Wq, Wk, Wv, Wo, WtQ, WtK, WtV, WtO);
    k_gemm_qkv<<<2304, 64, 0, stream>>>(rb, xb, WtQ, WtK, WtV, bq, bk, bv, qb, kb, vb);
    dim3 ga(NS / 64, NH, NB);
    k_attn<<<ga, 256, 0, stream>>>(qb, kb, vb, am, aob);
    k_gemm_out<<<768, 64, 0, stream>>>(aob, WtO, bo, out);
}

// Round 13
// 64.243 us; speedup vs baseline: 1.3136x; 1.3136x over previous
//
#include <hip/hip_runtime.h>
#include <hip/hip_bf16.h>
#include <math.h>

#define NB 2
#define NS 2048
#define NHID 768
#define NH 12
#define NDH 64
#define NWIN 128

typedef __attribute__((ext_vector_type(8))) short bf16x8;
typedef __attribute__((ext_vector_type(4))) float f32x4;

__device__ inline unsigned short f2b(float f) {
    union { float f; unsigned int i; } x; x.f = f;
    unsigned int r = x.i + 0x7FFFu + ((x.i >> 16) & 1u);   // RNE
    return (unsigned short)(r >> 16);
}
// XCD-chunked bijective remap (nwg % 8 == 0): XCD k gets contiguous chunk
__device__ inline int xcd_remap(int flat, int nwg) {
    return (flat & 7) * (nwg >> 3) + (flat >> 3);
}
// async global->LDS, 16B per lane (LDS dest = wave-uniform base + lane*16)
__device__ __forceinline__ void gload_lds16(const void* g, void* l) {
    __builtin_amdgcn_global_load_lds((const __attribute__((address_space(1))) void*)g,
                                     (__attribute__((address_space(3))) void*)l, 16, 0, 0);
}

union Frag { bf16x8 v; unsigned long long q[2]; uint4 u; };

// ---------------- fused prep: convT (blocks 0..575) + rope (blocks 576..6719) --------
__global__ __launch_bounds__(256) void k_prep(const float* __restrict__ x,
                                              __hip_bfloat16* __restrict__ rb,
                                              __hip_bfloat16* __restrict__ xb,
                                              const float* __restrict__ w0, const float* __restrict__ w1,
                                              const float* __restrict__ w2, const float* __restrict__ w3,
                                              __hip_bfloat16* o0, __hip_bfloat16* o1,
                                              __hip_bfloat16* o2, __hip_bfloat16* o3) {
    int bid = blockIdx.x;
    int t = threadIdx.x;
    if (bid < 576) {
        int wsel = bid / 144, r = bid % 144;
        int kx = r % 12, ny = r / 12;
        const float* W; __hip_bfloat16* O;
        switch (wsel) {
            case 0: W = w0; O = o0; break;
            case 1: W = w1; O = o1; break;
            case 2: W = w2; O = o2; break;
            default: W = w3; O = o3; break;
        }
        __shared__ float tile[64][65];
        int k0 = kx * 64, n0 = ny * 64;
        int rr = t >> 4, cc = (t & 15) * 4;
#pragma unroll
        for (int u = 0; u < 4; ++u) {
            int row = rr + u * 16;
            float4 f = *(const float4*)(W + (size_t)(k0 + row) * NHID + n0 + cc);
            tile[row][cc] = f.x; tile[row][cc + 1] = f.y;
            tile[row][cc + 2] = f.z; tile[row][cc + 3] = f.w;
        }
        __syncthreads();
#pragma unroll
        for (int u = 0; u < 4; ++u) {
            int n = rr + u * 16;
            ushort4 s = { f2b(tile[cc + 0][n]), f2b(tile[cc + 1][n]),
                          f2b(tile[cc + 2][n]), f2b(tile[cc + 3][n]) };
            *(ushort4*)((unsigned short*)O + (size_t)(n0 + n) * NHID + k0 + cc) = s;
        }
    } else {
        int idx = (bid - 576) * 256 + t;
        int f = idx & 31;
        int h = (idx >> 5) % NH;
        int bs = idx / (32 * NH);
        int s = bs & (NS - 1);
        int base = bs * NHID + h * NDH;
        float x1 = x[base + f], x2 = x[base + 32 + f];
        float inv = exp2f(-0.4152410118609203f * (float)f);   // 10000^(-f/32)
        float ang = (float)s * inv;
        float c = cosf(ang), sn = sinf(ang);
        ((unsigned short*)rb)[base + f]      = f2b(x1 * c - x2 * sn);
        ((unsigned short*)rb)[base + 32 + f] = f2b(x2 * c + x1 * sn);
        ((unsigned short*)xb)[base + f]      = f2b(x1);
        ((unsigned short*)xb)[base + 32 + f] = f2b(x2);
    }
}

// ---------------- bf16 MFMA GEMM body (R8/R11 structure — best measured) -------------
// Tile BM x 64 (BM = 32*MF), BK=64, 4 waves (2x2), single-buffer gload_lds,
// 2-barrier loop. Pipeline variants (dbuf R7/R9, counted-vmcnt R10, 1-wave R12)
// all neutral or worse: occupancy trades against latency hiding at this shape.
// Swizzle (rule #21): thread t stages global k-chunk (t&7)^(srow&7) -> linear LDS
// slot t&7; read chunk S of row r at phys slot S^(r&7), one ds_read_b128 each.
template<int MF>
__device__ __forceinline__ void gemm_body(const __hip_bfloat16* __restrict__ A,
                                          const __hip_bfloat16* __restrict__ Wt,
                                          const float* __restrict__ bias,
                                          __hip_bfloat16* __restrict__ Cb,
                                          float* __restrict__ Cf, float scale,
                                          int m0, int n0) {
    constexpr int BM = 32 * MF;
    __shared__ __attribute__((aligned(16))) unsigned short As[BM][64];
    __shared__ __attribute__((aligned(16))) unsigned short Bs[64][64];
    const int t = threadIdx.x;
    const int wid = t >> 6, lane = t & 63;
    const int wm = (wid >> 1) * 16 * MF, wn = (wid & 1) * 32;
    const int g = lane >> 4, r16 = lane & 15;
    const int swz = r16 & 7;

    f32x4 acc[MF][2];
#pragma unroll
    for (int i = 0; i < MF; ++i)
#pragma unroll
        for (int j = 0; j < 2; ++j) acc[i][j] = (f32x4){0.f, 0.f, 0.f, 0.f};

    const int srow = t >> 3;                       // 0..31
    const int gslot = (t & 7) ^ (srow & 7);        // inverse-swizzled source chunk
    const unsigned short* gA = (const unsigned short*)A + (size_t)(m0 + srow) * NHID + gslot * 8;
    const unsigned short* gB = (const unsigned short*)Wt + (size_t)(n0 + srow) * NHID + gslot * 8;
    char* lA = (char*)&As[0][0] + wid * 1024;      // wave-uniform LDS base
    char* lB = (char*)&Bs[0][0] + wid * 1024;

    for (int ks = 0; ks < NHID / 64; ++ks) {
        __syncthreads();                           // prev tile's reads done
#pragma unroll
        for (int c = 0; c < MF; ++c)
            gload_lds16(gA + (size_t)c * 32 * NHID + ks * 64, lA + c * 4096);
#pragma unroll
        for (int c = 0; c < 2; ++c)
            gload_lds16(gB + (size_t)c * 32 * NHID + ks * 64, lB + c * 4096);
        __syncthreads();                           // vmcnt drained: tile in LDS
#pragma unroll
        for (int kk = 0; kk < 2; ++kk) {
            Frag af[MF], bf[2];
#pragma unroll
            for (int mi = 0; mi < MF; ++mi)
                af[mi].u = *(const uint4*)&As[wm + mi * 16 + r16][((kk * 4 + g) ^ swz) * 8];
#pragma unroll
            for (int ni = 0; ni < 2; ++ni)
                bf[ni].u = *(const uint4*)&Bs[wn + ni * 16 + r16][((kk * 4 + g) ^ swz) * 8];
#pragma unroll
            for (int mi = 0; mi < MF; ++mi)
#pragma unroll
                for (int ni = 0; ni < 2; ++ni)
                    acc[mi][ni] = __builtin_amdgcn_mfma_f32_16x16x32_bf16(af[mi].v, bf[ni].v, acc[mi][ni], 0, 0, 0);
        }
    }

#pragma unroll
    for (int mi = 0; mi < MF; ++mi)
#pragma unroll
        for (int ni = 0; ni < 2; ++ni)
#pragma unroll
            for (int r = 0; r < 4; ++r) {
                int m = m0 + wm + mi * 16 + 4 * g + r;
                int n = n0 + wn + ni * 16 + r16;
                float v = (acc[mi][ni][r] + bias[n]) * scale;
                if (Cb) ((unsigned short*)Cb)[(size_t)m * NHID + n] = f2b(v);
                else    Cf[(size_t)m * NHID + n] = v;
            }
}

// fused QKV projection, XCD-chunked. Tile 128x64 -> 1152 blocks.
__global__ __launch_bounds__(256) void k_gemm_qkv(const __hip_bfloat16* __restrict__ rb,
                                                  const __hip_bfloat16* __restrict__ xb,
                                                  const __hip_bfloat16* __restrict__ WtQ,
                                                  const __hip_bfloat16* __restrict__ WtK,
                                                  const __hip_bfloat16* __restrict__ WtV,
                                                  const float* __restrict__ bq,
                                                  const float* __restrict__ bk,
                                                  const float* __restrict__ bv,
                                                  __hip_bfloat16* qb, __hip_bfloat16* kb,
                                                  __hip_bfloat16* vb) {
    int flat = blockIdx.x + 12 * blockIdx.y + 384 * blockIdx.z;
    int id = xcd_remap(flat, 1152);
    int z = id / 384, rem = id - z * 384;
    int ty = rem / 12, tx = rem - ty * 12;
    const __hip_bfloat16 *A, *W; const float* bias; __hip_bfloat16* C; float scale;
    switch (z) {
        case 0:  A = rb; W = WtQ; bias = bq; C = qb; scale = 0.125f; break;
        case 1:  A = rb; W = WtK; bias = bk; C = kb; scale = 1.0f;   break;
        default: A = xb; W = WtV; bias = bv; C = vb; scale = 1.0f;   break;
    }
    gemm_body<4>(A, W, bias, C, nullptr, scale, ty * 128, tx * 64);
}

// output projection, XCD-chunked. Tile 64x64 -> 768 blocks.
__global__ __launch_bounds__(256) void k_gemm_out(const __hip_bfloat16* __restrict__ A,
                                                  const __hip_bfloat16* __restrict__ Wt,
                                                  const float* __restrict__ bias,
                                                  float* __restrict__ Cf) {
    int flat = blockIdx.x + 12 * blockIdx.y;
    int id = xcd_remap(flat, 768);
    int ty = id / 12, tx = id - ty * 12;
    gemm_body<2>(A, Wt, bias, nullptr, Cf, 1.0f, ty * 64, tx * 64);
}

// ---------------- sliding-window flash attention, MFMA + T14 + LDS dbuf --------------
// Double-buffered Ks/Vt/kmask (37KB; grid-limited at 3 blocks/CU so LDS is free),
// ONE barrier per K/V tile: iteration kt writes buf kt&1, lgkmcnt(0)+raw barrier,
// computes. Next iteration's writes target buf (kt+1)&1 whose readers (tile kt-1)
// are provably done: each wave's own lgkmcnt(0) precedes the tile-kt barrier.
// T14: next tile's global loads issued before compute, fly across the barrier.
__global__ __launch_bounds__(256) void k_attn(const __hip_bfloat16* __restrict__ q,
                                              const __hip_bfloat16* __restrict__ kmat,
                                              const __hip_bfloat16* __restrict__ vmat,
                                              const int* __restrict__ am,
                                              __hip_bfloat16* __restrict__ o) {
    __shared__ unsigned short Ks[2][64][72];   // [buf][key][d]
    __shared__ unsigned short Vt[2][64][72];   // [buf][d][key]
    __shared__ float kmask[2][64];
    const int t = threadIdx.x;
    const int h = blockIdx.y, b = blockIdx.z;
    const int i0 = blockIdx.x * 64;
    const int w = t >> 6, lane = t & 63;
    const int g = lane >> 4, r16 = lane & 15;
    const int qrow = i0 + w * 16 + r16;

    Frag qf[2];
    {
        const unsigned short* qp = (const unsigned short*)q + ((size_t)(b * NS) + qrow) * NHID + h * NDH;
        qf[0].q[0] = *(const unsigned long long*)(qp + 4 * g);
        qf[0].q[1] = *(const unsigned long long*)(qp + 16 + 4 * g);
        qf[1].q[0] = *(const unsigned long long*)(qp + 32 + 4 * g);
        qf[1].q[1] = *(const unsigned long long*)(qp + 48 + 4 * g);
    }
    float m_run = -1e30f, l_run = 0.f;
    f32x4 oacc[4];
#pragma unroll
    for (int i = 0; i < 4; ++i) oacc[i] = (f32x4){0.f, 0.f, 0.f, 0.f};

    const int ktL = (i0 == 0) ? 2 : (i0 == 64) ? 1 : 0;
    const int ktH = (i0 == NS - 64) ? 2 : (i0 == NS - 128) ? 3 : 4;

    uint4 pK0, pK1, pV0, pV1; float pm = 0.f;

#define LOADREGS(KT) do {                                                        \
    int j0_ = i0 - 128 + (KT) * 64;                                              \
    const unsigned short* kp_ = (const unsigned short*)kmat +                    \
        ((size_t)(b * NS) + j0_ + (t >> 2)) * NHID + h * NDH + (t & 3) * 16;     \
    pK0 = *(const uint4*)kp_;                                                    \
    pK1 = *(const uint4*)(kp_ + 8);                                              \
    const unsigned short* vp_ = (const unsigned short*)vmat +                    \
        ((size_t)(b * NS) + j0_ + 2 * (t & 31)) * NHID + h * NDH + (t >> 5) * 8; \
    pV0 = *(const uint4*)vp_;                                                    \
    pV1 = *(const uint4*)(vp_ + NHID);                                           \
    if (t < 64) pm = (am[b * NS + j0_ + t] != 0) ? 0.f : -1e30f;                 \
} while (0)

    LOADREGS(ktL);
    for (int kt = ktL; kt <= ktH; ++kt) {
        const int j0 = i0 - 128 + kt * 64;
        const int b2 = kt & 1;
        {   // write staged regs -> LDS buf b2 (K row-major; V transposed paired-b32)
            *(uint4*)&Ks[b2][t >> 2][(t & 3) * 16]     = pK0;
            *(uint4*)&Ks[b2][t >> 2][(t & 3) * 16 + 8] = pK1;
            union { uint4 u; unsigned short s[8]; } a0, a1;
            a0.u = pV0; a1.u = pV1;
#pragma unroll
            for (int e = 0; e < 8; ++e) {
                unsigned int pk = (unsigned int)a0.s[e] | ((unsigned int)a1.s[e] << 16);
                *(unsigned int*)&Vt[b2][(t >> 5) * 8 + e][2 * (t & 31)] = pk;
            }
            if (t < 64) kmask[b2][t] = pm;
        }
        if (kt < ktH) LOADREGS(kt + 1);        // prefetch flies across the barrier
        asm volatile("s_waitcnt lgkmcnt(0)" ::: "memory");
        __builtin_amdgcn_s_barrier();          // single barrier per tile (dbuf)

        // S^T = K . Q^T
        f32x4 sacc[4];
#pragma unroll
        for (int i = 0; i < 4; ++i) sacc[i] = (f32x4){0.f, 0.f, 0.f, 0.f};
#pragma unroll
        for (int mi = 0; mi < 4; ++mi) {
            Frag kf0, kf1;
            const unsigned short* pk = &Ks[b2][mi * 16 + r16][0];
            kf0.q[0] = *(const unsigned long long*)(pk + 4 * g);
            kf0.q[1] = *(const unsigned long long*)(pk + 16 + 4 * g);
            kf1.q[0] = *(const unsigned long long*)(pk + 32 + 4 * g);
            kf1.q[1] = *(const unsigned long long*)(pk + 48 + 4 * g);
            sacc[mi] = __builtin_amdgcn_mfma_f32_16x16x32_bf16(kf0.v, qf[0].v, sacc[mi], 0, 0, 0);
            sacc[mi] = __builtin_amdgcn_mfma_f32_16x16x32_bf16(kf1.v, qf[1].v, sacc[mi], 0, 0, 0);
        }

        // mask + per-lane online softmax
        float p[4][4];
        float tmax = -1e30f;
#pragma unroll
        for (int mi = 0; mi < 4; ++mi)
#pragma unroll
            for (int r = 0; r < 4; ++r) {
                int key = j0 + mi * 16 + 4 * g + r;
                float s = sacc[mi][r] + kmask[b2][mi * 16 + 4 * g + r];
                int d = qrow - key; d = d < 0 ? -d : d;
                if (d >= NWIN) s = -1e30f;
                p[mi][r] = s;
                tmax = fmaxf(tmax, s);
            }
        tmax = fmaxf(tmax, __shfl_xor(tmax, 16));
        tmax = fmaxf(tmax, __shfl_xor(tmax, 32));
        float mnew = fmaxf(m_run, tmax);
        float psum = 0.f;
#pragma unroll
        for (int mi = 0; mi < 4; ++mi)
#pragma unroll
            for (int r = 0; r < 4; ++r) {
                float pv = __expf(p[mi][r] - mnew);
                p[mi][r] = pv;
                psum += pv;
            }
        psum += __shfl_xor(psum, 16);
        psum += __shfl_xor(psum, 32);
        float alpha = __expf(m_run - mnew);
        m_run = mnew;
        l_run = l_run * alpha + psum;
#pragma unroll
        for (int mi = 0; mi < 4; ++mi)
#pragma unroll
            for (int r = 0; r < 4; ++r) oacc[mi][r] *= alpha;

        // pack P^T fragments (in-lane)
        Frag pf[2];
#pragma unroll
        for (int ks2 = 0; ks2 < 2; ++ks2) {
            union { bf16x8 v; unsigned short s[8]; } pp;
#pragma unroll
            for (int r = 0; r < 4; ++r) {
                pp.s[r]     = f2b(p[2 * ks2][r]);
                pp.s[r + 4] = f2b(p[2 * ks2 + 1][r]);
            }
            pf[ks2].v = pp.v;
        }

        // O^T += V^T . P^T
#pragma unroll
        for (int mi = 0; mi < 4; ++mi) {
            Frag vf0, vf1;
            const unsigned short* pv = &Vt[b2][mi * 16 + r16][0];
            vf0.q[0] = *(const unsigned long long*)(pv + 4 * g);
            vf0.q[1] = *(const unsigned long long*)(pv + 16 + 4 * g);
            vf1.q[0] = *(const unsigned long long*)(pv + 32 + 4 * g);
            vf1.q[1] = *(const unsigned long long*)(pv + 48 + 4 * g);
            oacc[mi] = __builtin_amdgcn_mfma_f32_16x16x32_bf16(vf0.v, pf[0].v, oacc[mi], 0, 0, 0);
            oacc[mi] = __builtin_amdgcn_mfma_f32_16x16x32_bf16(vf1.v, pf[1].v, oacc[mi], 0, 0, 0);
        }
        // no trailing barrier: next iteration writes the OTHER buffer, whose
        // readers completed before this tile's barrier (per-wave lgkmcnt(0)).
    }
#undef LOADREGS

    float inv_l = 1.0f / l_run;
    unsigned short* op = (unsigned short*)o + ((size_t)(b * NS) + qrow) * NHID + h * NDH;
#pragma unroll
    for (int mi = 0; mi < 4; ++mi) {
        ushort4 s = { f2b(oacc[mi][0] * inv_l), f2b(oacc[mi][1] * inv_l),
                      f2b(oacc[mi][2] * inv_l), f2b(oacc[mi][3] * inv_l) };
        *(ushort4*)(op + mi * 16 + 4 * g) = s;
    }
}

extern "C" void kernel_launch(void* const* d_in, const int* in_sizes, int n_in,
                              void* d_out, int out_size, void* d_ws, size_t ws_size,
                              hipStream_t stream) {
    (void)in_sizes; (void)n_in; (void)out_size; (void)ws_size;
    const float* x  = (const float*)d_in[0];
    const int*   am = (const int*)d_in[1];
    const float* Wq = (const float*)d_in[2];
    const float* bq = (const float*)d_in[3];
    const float* Wk = (const float*)d_in[4];
    const float* bk = (const float*)d_in[5];
    const float* Wv = (const float*)d_in[6];
    const float* bv = (const float*)d_in[7];
    const float* Wo = (const float*)d_in[8];
    const float* bo = (const float*)d_in[9];
    float* out = (float*)d_out;
    float* ws  = (float*)d_ws;

    __hip_bfloat16* rb  = (__hip_bfloat16*)(ws);             // 4096x768 bf16
    __hip_bfloat16* xb  = (__hip_bfloat16*)(ws + 1572864);
    __hip_bfloat16* WtQ = (__hip_bfloat16*)(ws + 3145728);   // 768x768 bf16 each
    __hip_bfloat16* WtK = (__hip_bfloat16*)(ws + 3440640);
    __hip_bfloat16* WtV = (__hip_bfloat16*)(ws + 3735552);
    __hip_bfloat16* WtO = (__hip_bfloat16*)(ws + 4030464);
    __hip_bfloat16* qb  = (__hip_bfloat16*)(ws + 4325376);   // 4096x768 bf16 each
    __hip_bfloat16* kb  = (__hip_bfloat16*)(ws + 5898240);
    __hip_bfloat16* vb  = (__hip_bfloat16*)(ws + 7471104);
    __hip_bfloat16* aob = (__hip_bfloat16*)(ws + 9043968);

    k_prep<<<576 + 6144, 256, 0, stream>>>(x, rb, xb, Wq, Wk, Wv, Wo, WtQ, WtK, WtV, WtO);
    dim3 gq(NHID / 64, NB * NS / 128, 3);
    k_gemm_qkv<<<gq, 256, 0, stream>>>(rb, xb, WtQ, WtK, WtV, bq, bk, bv, qb, kb, vb);
    dim3 ga(NS / 64, NH, NB);
    k_attn<<<ga, 256, 0, stream>>>(qb, kb, vb, am, aob);
    dim3 gg(NHID / 64, NB * NS / 64);
    k_gemm_out<<<gg, 256, 0, stream>>>(aob, WtO, bo, out);
}

// Round 14
// 64.015 us; speedup vs baseline: 1.3183x; 1.0036x over previous
//
#include <hip/hip_runtime.h>
#include <hip/hip_bf16.h>
#include <math.h>

#define NB 2
#define NS 2048
#define NHID 768
#define NH 12
#define NDH 64
#define NWIN 128

typedef __attribute__((ext_vector_type(8))) short bf16x8;
typedef __attribute__((ext_vector_type(4))) float f32x4;

__device__ inline unsigned short f2b(float f) {
    union { float f; unsigned int i; } x; x.f = f;
    unsigned int r = x.i + 0x7FFFu + ((x.i >> 16) & 1u);   // RNE
    return (unsigned short)(r >> 16);
}
// XCD-chunked bijective remap (nwg % 8 == 0): XCD k gets contiguous chunk
__device__ inline int xcd_remap(int flat, int nwg) {
    return (flat & 7) * (nwg >> 3) + (flat >> 3);
}
// async global->LDS, 16B per lane (LDS dest = wave-uniform base + lane*16)
__device__ __forceinline__ void gload_lds16(const void* g, void* l) {
    __builtin_amdgcn_global_load_lds((const __attribute__((address_space(1))) void*)g,
                                     (__attribute__((address_space(3))) void*)l, 16, 0, 0);
}

union Frag { bf16x8 v; unsigned long long q[2]; uint4 u; };

// ---------------- fused prep: convT (blocks 0..575) + rope (blocks 576..6719) --------
__global__ __launch_bounds__(256) void k_prep(const float* __restrict__ x,
                                              __hip_bfloat16* __restrict__ rb,
                                              __hip_bfloat16* __restrict__ xb,
                                              const float* __restrict__ w0, const float* __restrict__ w1,
                                              const float* __restrict__ w2, const float* __restrict__ w3,
                                              __hip_bfloat16* o0, __hip_bfloat16* o1,
                                              __hip_bfloat16* o2, __hip_bfloat16* o3) {
    int bid = blockIdx.x;
    int t = threadIdx.x;
    if (bid < 576) {
        int wsel = bid / 144, r = bid % 144;
        int kx = r % 12, ny = r / 12;
        const float* W; __hip_bfloat16* O;
        switch (wsel) {
            case 0: W = w0; O = o0; break;
            case 1: W = w1; O = o1; break;
            case 2: W = w2; O = o2; break;
            default: W = w3; O = o3; break;
        }
        __shared__ float tile[64][65];
        int k0 = kx * 64, n0 = ny * 64;
        int rr = t >> 4, cc = (t & 15) * 4;
#pragma unroll
        for (int u = 0; u < 4; ++u) {
            int row = rr + u * 16;
            float4 f = *(const float4*)(W + (size_t)(k0 + row) * NHID + n0 + cc);
            tile[row][cc] = f.x; tile[row][cc + 1] = f.y;
            tile[row][cc + 2] = f.z; tile[row][cc + 3] = f.w;
        }
        __syncthreads();
#pragma unroll
        for (int u = 0; u < 4; ++u) {
            int n = rr + u * 16;
            ushort4 s = { f2b(tile[cc + 0][n]), f2b(tile[cc + 1][n]),
                          f2b(tile[cc + 2][n]), f2b(tile[cc + 3][n]) };
            *(ushort4*)((unsigned short*)O + (size_t)(n0 + n) * NHID + k0 + cc) = s;
        }
    } else {
        int idx = (bid - 576) * 256 + t;
        int f = idx & 31;
        int h = (idx >> 5) % NH;
        int bs = idx / (32 * NH);
        int s = bs & (NS - 1);
        int base = bs * NHID + h * NDH;
        float x1 = x[base + f], x2 = x[base + 32 + f];
        float inv = exp2f(-0.4152410118609203f * (float)f);   // 10000^(-f/32)
        float ang = (float)s * inv;
        float c = cosf(ang), sn = sinf(ang);
        ((unsigned short*)rb)[base + f]      = f2b(x1 * c - x2 * sn);
        ((unsigned short*)rb)[base + 32 + f] = f2b(x2 * c + x1 * sn);
        ((unsigned short*)xb)[base + f]      = f2b(x1);
        ((unsigned short*)xb)[base + 32 + f] = f2b(x2);
    }
}

// ---------------- 128x128 MFMA GEMM (qkv): gload_lds + swizzle, 2-barrier loop -------
// 4 waves (2x2 of 64x64). Staged-bytes/output = 2 B (vs 3 at 128x64); per K-step
// 32 MFMA : 8 DMA (vs 16 : 6). LDS 32 KB. Swizzle per rule #21 (source-permuted,
// linear dest, XOR on read).
__device__ __forceinline__ void gemm128(const __hip_bfloat16* __restrict__ A,
                                        const __hip_bfloat16* __restrict__ Wt,
                                        const float* __restrict__ bias,
                                        __hip_bfloat16* __restrict__ Cb,
                                        float scale, int m0, int n0) {
    __shared__ __attribute__((aligned(16))) unsigned short As[128][64];
    __shared__ __attribute__((aligned(16))) unsigned short Bs[128][64];
    const int t = threadIdx.x;
    const int wid = t >> 6, lane = t & 63;
    const int wm = (wid >> 1) * 64, wn = (wid & 1) * 64;
    const int g = lane >> 4, r16 = lane & 15;
    const int swz = r16 & 7;

    f32x4 acc[4][4];
#pragma unroll
    for (int i = 0; i < 4; ++i)
#pragma unroll
        for (int j = 0; j < 4; ++j) acc[i][j] = (f32x4){0.f, 0.f, 0.f, 0.f};

    const int srow = t >> 3;                       // 0..31
    const int gslot = (t & 7) ^ (srow & 7);        // inverse-swizzled source chunk
    const unsigned short* gA = (const unsigned short*)A + (size_t)(m0 + srow) * NHID + gslot * 8;
    const unsigned short* gB = (const unsigned short*)Wt + (size_t)(n0 + srow) * NHID + gslot * 8;
    char* lA = (char*)&As[0][0] + wid * 1024;      // wave-uniform LDS base
    char* lB = (char*)&Bs[0][0] + wid * 1024;

    for (int ks = 0; ks < NHID / 64; ++ks) {
        __syncthreads();                           // prev tile's reads done
#pragma unroll
        for (int c = 0; c < 4; ++c)
            gload_lds16(gA + (size_t)c * 32 * NHID + ks * 64, lA + c * 4096);
#pragma unroll
        for (int c = 0; c < 4; ++c)
            gload_lds16(gB + (size_t)c * 32 * NHID + ks * 64, lB + c * 4096);
        __syncthreads();                           // vmcnt drained: tile in LDS
#pragma unroll
        for (int kk = 0; kk < 2; ++kk) {
            Frag af[4], bf[4];
#pragma unroll
            for (int mi = 0; mi < 4; ++mi)
                af[mi].u = *(const uint4*)&As[wm + mi * 16 + r16][((kk * 4 + g) ^ swz) * 8];
#pragma unroll
            for (int ni = 0; ni < 4; ++ni)
                bf[ni].u = *(const uint4*)&Bs[wn + ni * 16 + r16][((kk * 4 + g) ^ swz) * 8];
#pragma unroll
            for (int mi = 0; mi < 4; ++mi)
#pragma unroll
                for (int ni = 0; ni < 4; ++ni)
                    acc[mi][ni] = __builtin_amdgcn_mfma_f32_16x16x32_bf16(af[mi].v, bf[ni].v, acc[mi][ni], 0, 0, 0);
        }
    }

#pragma unroll
    for (int mi = 0; mi < 4; ++mi)
#pragma unroll
        for (int ni = 0; ni < 4; ++ni)
#pragma unroll
            for (int r = 0; r < 4; ++r) {
                int m = m0 + wm + mi * 16 + 4 * g + r;
                int n = n0 + wn + ni * 16 + r16;
                float v = (acc[mi][ni][r] + bias[n]) * scale;
                ((unsigned short*)Cb)[(size_t)m * NHID + n] = f2b(v);
            }
}

// fused QKV projection, XCD-chunked. Tile 128x128 -> 576 blocks.
__global__ __launch_bounds__(256) void k_gemm_qkv(const __hip_bfloat16* __restrict__ rb,
                                                  const __hip_bfloat16* __restrict__ xb,
                                                  const __hip_bfloat16* __restrict__ WtQ,
                                                  const __hip_bfloat16* __restrict__ WtK,
                                                  const __hip_bfloat16* __restrict__ WtV,
                                                  const float* __restrict__ bq,
                                                  const float* __restrict__ bk,
                                                  const float* __restrict__ bv,
                                                  __hip_bfloat16* qb, __hip_bfloat16* kb,
                                                  __hip_bfloat16* vb) {
    int flat = blockIdx.x + 6 * blockIdx.y + 192 * blockIdx.z;
    int id = xcd_remap(flat, 576);
    int z = id / 192, rem = id - z * 192;
    int ty = rem / 6, tx = rem - ty * 6;
    const __hip_bfloat16 *A, *W; const float* bias; __hip_bfloat16* C; float scale;
    switch (z) {
        case 0:  A = rb; W = WtQ; bias = bq; C = qb; scale = 0.125f; break;
        case 1:  A = rb; W = WtK; bias = bk; C = kb; scale = 1.0f;   break;
        default: A = xb; W = WtV; bias = bv; C = vb; scale = 1.0f;   break;
    }
    gemm128(A, W, bias, C, scale, ty * 128, tx * 128);
}

// ---------------- 64-wide GEMM body (out-proj; R11 best-measured config) -------------
template<int MF>
__device__ __forceinline__ void gemm_body(const __hip_bfloat16* __restrict__ A,
                                          const __hip_bfloat16* __restrict__ Wt,
                                          const float* __restrict__ bias,
                                          __hip_bfloat16* __restrict__ Cb,
                                          float* __restrict__ Cf, float scale,
                                          int m0, int n0) {
    constexpr int BM = 32 * MF;
    __shared__ __attribute__((aligned(16))) unsigned short As[BM][64];
    __shared__ __attribute__((aligned(16))) unsigned short Bs[64][64];
    const int t = threadIdx.x;
    const int wid = t >> 6, lane = t & 63;
    const int wm = (wid >> 1) * 16 * MF, wn = (wid & 1) * 32;
    const int g = lane >> 4, r16 = lane & 15;
    const int swz = r16 & 7;

    f32x4 acc[MF][2];
#pragma unroll
    for (int i = 0; i < MF; ++i)
#pragma unroll
        for (int j = 0; j < 2; ++j) acc[i][j] = (f32x4){0.f, 0.f, 0.f, 0.f};

    const int srow = t >> 3;
    const int gslot = (t & 7) ^ (srow & 7);
    const unsigned short* gA = (const unsigned short*)A + (size_t)(m0 + srow) * NHID + gslot * 8;
    const unsigned short* gB = (const unsigned short*)Wt + (size_t)(n0 + srow) * NHID + gslot * 8;
    char* lA = (char*)&As[0][0] + wid * 1024;
    char* lB = (char*)&Bs[0][0] + wid * 1024;

    for (int ks = 0; ks < NHID / 64; ++ks) {
        __syncthreads();
#pragma unroll
        for (int c = 0; c < MF; ++c)
            gload_lds16(gA + (size_t)c * 32 * NHID + ks * 64, lA + c * 4096);
#pragma unroll
        for (int c = 0; c < 2; ++c)
            gload_lds16(gB + (size_t)c * 32 * NHID + ks * 64, lB + c * 4096);
        __syncthreads();
#pragma unroll
        for (int kk = 0; kk < 2; ++kk) {
            Frag af[MF], bf[2];
#pragma unroll
            for (int mi = 0; mi < MF; ++mi)
                af[mi].u = *(const uint4*)&As[wm + mi * 16 + r16][((kk * 4 + g) ^ swz) * 8];
#pragma unroll
            for (int ni = 0; ni < 2; ++ni)
                bf[ni].u = *(const uint4*)&Bs[wn + ni * 16 + r16][((kk * 4 + g) ^ swz) * 8];
#pragma unroll
            for (int mi = 0; mi < MF; ++mi)
#pragma unroll
                for (int ni = 0; ni < 2; ++ni)
                    acc[mi][ni] = __builtin_amdgcn_mfma_f32_16x16x32_bf16(af[mi].v, bf[ni].v, acc[mi][ni], 0, 0, 0);
        }
    }

#pragma unroll
    for (int mi = 0; mi < MF; ++mi)
#pragma unroll
        for (int ni = 0; ni < 2; ++ni)
#pragma unroll
            for (int r = 0; r < 4; ++r) {
                int m = m0 + wm + mi * 16 + 4 * g + r;
                int n = n0 + wn + ni * 16 + r16;
                float v = (acc[mi][ni][r] + bias[n]) * scale;
                if (Cb) ((unsigned short*)Cb)[(size_t)m * NHID + n] = f2b(v);
                else    Cf[(size_t)m * NHID + n] = v;
            }
}

// output projection, XCD-chunked. Tile 64x64 -> 768 blocks.
__global__ __launch_bounds__(256) void k_gemm_out(const __hip_bfloat16* __restrict__ A,
                                                  const __hip_bfloat16* __restrict__ Wt,
                                                  const float* __restrict__ bias,
                                                  float* __restrict__ Cf) {
    int flat = blockIdx.x + 12 * blockIdx.y;
    int id = xcd_remap(flat, 768);
    int ty = id / 12, tx = id - ty * 12;
    gemm_body<2>(A, Wt, bias, nullptr, Cf, 1.0f, ty * 64, tx * 64);
}

// ---------------- sliding-window flash attention, MFMA + T14 + LDS dbuf (R13) --------
__global__ __launch_bounds__(256) void k_attn(const __hip_bfloat16* __restrict__ q,
                                              const __hip_bfloat16* __restrict__ kmat,
                                              const __hip_bfloat16* __restrict__ vmat,
                                              const int* __restrict__ am,
                                              __hip_bfloat16* __restrict__ o) {
    __shared__ unsigned short Ks[2][64][72];   // [buf][key][d]
    __shared__ unsigned short Vt[2][64][72];   // [buf][d][key]
    __shared__ float kmask[2][64];
    const int t = threadIdx.x;
    const int h = blockIdx.y, b = blockIdx.z;
    const int i0 = blockIdx.x * 64;
    const int w = t >> 6, lane = t & 63;
    const int g = lane >> 4, r16 = lane & 15;
    const int qrow = i0 + w * 16 + r16;

    Frag qf[2];
    {
        const unsigned short* qp = (const unsigned short*)q + ((size_t)(b * NS) + qrow) * NHID + h * NDH;
        qf[0].q[0] = *(const unsigned long long*)(qp + 4 * g);
        qf[0].q[1] = *(const unsigned long long*)(qp + 16 + 4 * g);
        qf[1].q[0] = *(const unsigned long long*)(qp + 32 + 4 * g);
        qf[1].q[1] = *(const unsigned long long*)(qp + 48 + 4 * g);
    }
    float m_run = -1e30f, l_run = 0.f;
    f32x4 oacc[4];
#pragma unroll
    for (int i = 0; i < 4; ++i) oacc[i] = (f32x4){0.f, 0.f, 0.f, 0.f};

    const int ktL = (i0 == 0) ? 2 : (i0 == 64) ? 1 : 0;
    const int ktH = (i0 == NS - 64) ? 2 : (i0 == NS - 128) ? 3 : 4;

    uint4 pK0, pK1, pV0, pV1; float pm = 0.f;

#define LOADREGS(KT) do {                                                        \
    int j0_ = i0 - 128 + (KT) * 64;                                              \
    const unsigned short* kp_ = (const unsigned short*)kmat +                    \
        ((size_t)(b * NS) + j0_ + (t >> 2)) * NHID + h * NDH + (t & 3) * 16;     \
    pK0 = *(const uint4*)kp_;                                                    \
    pK1 = *(const uint4*)(kp_ + 8);                                              \
    const unsigned short* vp_ = (const unsigned short*)vmat +                    \
        ((size_t)(b * NS) + j0_ + 2 * (t & 31)) * NHID + h * NDH + (t >> 5) * 8; \
    pV0 = *(const uint4*)vp_;                                                    \
    pV1 = *(const uint4*)(vp_ + NHID);                                           \
    if (t < 64) pm = (am[b * NS + j0_ + t] != 0) ? 0.f : -1e30f;                 \
} while (0)

    LOADREGS(ktL);
    for (int kt = ktL; kt <= ktH; ++kt) {
        const int j0 = i0 - 128 + kt * 64;
        const int b2 = kt & 1;
        {
            *(uint4*)&Ks[b2][t >> 2][(t & 3) * 16]     = pK0;
            *(uint4*)&Ks[b2][t >> 2][(t & 3) * 16 + 8] = pK1;
            union { uint4 u; unsigned short s[8]; } a0, a1;
            a0.u = pV0; a1.u = pV1;
#pragma unroll
            for (int e = 0; e < 8; ++e) {
                unsigned int pk = (unsigned int)a0.s[e] | ((unsigned int)a1.s[e] << 16);
                *(unsigned int*)&Vt[b2][(t >> 5) * 8 + e][2 * (t & 31)] = pk;
            }
            if (t < 64) kmask[b2][t] = pm;
        }
        if (kt < ktH) LOADREGS(kt + 1);
        asm volatile("s_waitcnt lgkmcnt(0)" ::: "memory");
        __builtin_amdgcn_s_barrier();

        f32x4 sacc[4];
#pragma unroll
        for (int i = 0; i < 4; ++i) sacc[i] = (f32x4){0.f, 0.f, 0.f, 0.f};
#pragma unroll
        for (int mi = 0; mi < 4; ++mi) {
            Frag kf0, kf1;
            const unsigned short* pk = &Ks[b2][mi * 16 + r16][0];
            kf0.q[0] = *(const unsigned long long*)(pk + 4 * g);
            kf0.q[1] = *(const unsigned long long*)(pk + 16 + 4 * g);
            kf1.q[0] = *(const unsigned long long*)(pk + 32 + 4 * g);
            kf1.q[1] = *(const unsigned long long*)(pk + 48 + 4 * g);
            sacc[mi] = __builtin_amdgcn_mfma_f32_16x16x32_bf16(kf0.v, qf[0].v, sacc[mi], 0, 0, 0);
            sacc[mi] = __builtin_amdgcn_mfma_f32_16x16x32_bf16(kf1.v, qf[1].v, sacc[mi], 0, 0, 0);
        }

        float p[4][4];
        float tmax = -1e30f;
#pragma unroll
        for (int mi = 0; mi < 4; ++mi)
#pragma unroll
            for (int r = 0; r < 4; ++r) {
                int key = j0 + mi * 16 + 4 * g + r;
                float s = sacc[mi][r] + kmask[b2][mi * 16 + 4 * g + r];
                int d = qrow - key; d = d < 0 ? -d : d;
                if (d >= NWIN) s = -1e30f;
                p[mi][r] = s;
                tmax = fmaxf(tmax, s);
            }
        tmax = fmaxf(tmax, __shfl_xor(tmax, 16));
        tmax = fmaxf(tmax, __shfl_xor(tmax, 32));
        float mnew = fmaxf(m_run, tmax);
        float psum = 0.f;
#pragma unroll
        for (int mi = 0; mi < 4; ++mi)
#pragma unroll
            for (int r = 0; r < 4; ++r) {
                float pv = __expf(p[mi][r] - mnew);
                p[mi][r] = pv;
                psum += pv;
            }
        psum += __shfl_xor(psum, 16);
        psum += __shfl_xor(psum, 32);
        float alpha = __expf(m_run - mnew);
        m_run = mnew;
        l_run = l_run * alpha + psum;
#pragma unroll
        for (int mi = 0; mi < 4; ++mi)
#pragma unroll
            for (int r = 0; r < 4; ++r) oacc[mi][r] *= alpha;

        Frag pf[2];
#pragma unroll
        for (int ks2 = 0; ks2 < 2; ++ks2) {
            union { bf16x8 v; unsigned short s[8]; } pp;
#pragma unroll
            for (int r = 0; r < 4; ++r) {
                pp.s[r]     = f2b(p[2 * ks2][r]);
                pp.s[r + 4] = f2b(p[2 * ks2 + 1][r]);
            }
            pf[ks2].v = pp.v;
        }

#pragma unroll
        for (int mi = 0; mi < 4; ++mi) {
            Frag vf0, vf1;
            const unsigned short* pv = &Vt[b2][mi * 16 + r16][0];
            vf0.q[0] = *(const unsigned long long*)(pv + 4 * g);
            vf0.q[1] = *(const unsigned long long*)(pv + 16 + 4 * g);
            vf1.q[0] = *(const unsigned long long*)(pv + 32 + 4 * g);
            vf1.q[1] = *(const unsigned long long*)(pv + 48 + 4 * g);
            oacc[mi] = __builtin_amdgcn_mfma_f32_16x16x32_bf16(vf0.v, pf[0].v, oacc[mi], 0, 0, 0);
            oacc[mi] = __builtin_amdgcn_mfma_f32_16x16x32_bf16(vf1.v, pf[1].v, oacc[mi], 0, 0, 0);
        }
    }
#undef LOADREGS

    float inv_l = 1.0f / l_run;
    unsigned short* op = (unsigned short*)o + ((size_t)(b * NS) + qrow) * NHID + h * NDH;
#pragma unroll
    for (int mi = 0; mi < 4; ++mi) {
        ushort4 s = { f2b(oacc[mi][0] * inv_l), f2b(oacc[mi][1] * inv_l),
                      f2b(oacc[mi][2] * inv_l), f2b(oacc[mi][3] * inv_l) };
        *(ushort4*)(op + mi * 16 + 4 * g) = s;
    }
}

extern "C" void kernel_launch(void* const* d_in, const int* in_sizes, int n_in,
                              void* d_out, int out_size, void* d_ws, size_t ws_size,
                              hipStream_t stream) {
    (void)in_sizes; (void)n_in; (void)out_size; (void)ws_size;
    const float* x  = (const float*)d_in[0];
    const int*   am = (const int*)d_in[1];
    const float* Wq = (const float*)d_in[2];
    const float* bq = (const float*)d_in[3];
    const float* Wk = (const float*)d_in[4];
    const float* bk = (const float*)d_in[5];
    const float* Wv = (const float*)d_in[6];
    const float* bv = (const float*)d_in[7];
    const float* Wo = (const float*)d_in[8];
    const float* bo = (const float*)d_in[9];
    float* out = (float*)d_out;
    float* ws  = (float*)d_ws;

    __hip_bfloat16* rb  = (__hip_bfloat16*)(ws);             // 4096x768 bf16
    __hip_bfloat16* xb  = (__hip_bfloat16*)(ws + 1572864);
    __hip_bfloat16* WtQ = (__hip_bfloat16*)(ws + 3145728);   // 768x768 bf16 each
    __hip_bfloat16* WtK = (__hip_bfloat16*)(ws + 3440640);
    __hip_bfloat16* WtV = (__hip_bfloat16*)(ws + 3735552);
    __hip_bfloat16* WtO = (__hip_bfloat16*)(ws + 4030464);
    __hip_bfloat16* qb  = (__hip_bfloat16*)(ws + 4325376);   // 4096x768 bf16 each
    __hip_bfloat16* kb  = (__hip_bfloat16*)(ws + 5898240);
    __hip_bfloat16* vb  = (__hip_bfloat16*)(ws + 7471104);
    __hip_bfloat16* aob = (__hip_bfloat16*)(ws + 9043968);

    k_prep<<<576 + 6144, 256, 0, stream>>>(x, rb, xb, Wq, Wk, Wv, Wo, WtQ, WtK, WtV, WtO);
    dim3 gq(6, 32, 3);
    k_gemm_qkv<<<gq, 256, 0, stream>>>(rb, xb, WtQ, WtK, WtV, bq, bk, bv, qb, kb, vb);
    dim3 ga(NS / 64, NH, NB);
    k_attn<<<ga, 256, 0, stream>>>(qb, kb, vb, am, aob);
    dim3 gg(NHID / 64, NB * NS / 64);
    k_gemm_out<<<gg, 256, 0, stream>>>(aob, WtO, bo, out);
}